// Round 8
// baseline (105.754 us; speedup 1.0000x reference)
//
#include <hip/hip_runtime.h>
#include <hip/hip_bf16.h>
#include <cmath>

#define T_DIM 2048
#define B_DIM 16
#define D_DIM 256
#define BD (B_DIM * D_DIM)
#define BMA 128           // t-rows per block
#define BNA 64            // s-rows per stage
#define NS 4              // s-chunks, chunk = 512
#define CHUNK (T_DIM / NS)
#define NEG_INF_F (-1e30f)
#define SCALE_LOG2 14.4269504088896f  // 10 / ln(2): logits in log2 domain
#define LN2F 0.6931471805599453f

typedef __attribute__((ext_vector_type(8))) short bf16x8;
typedef __attribute__((ext_vector_type(8))) unsigned short ushort8;
typedef __attribute__((ext_vector_type(4))) float f32x4;

static __device__ __forceinline__ ushort f2bf(float f) {
    union { float f; unsigned int u; } x; x.f = f;
    unsigned int r = (x.u + 0x7FFFu + ((x.u >> 16) & 1u)) >> 16;  // RNE
    return (ushort)r;
}

static __device__ __forceinline__ void gload_lds16(const ushort* g, ushort* l) {
    __builtin_amdgcn_global_load_lds(
        (const __attribute__((address_space(1))) unsigned int*)g,
        (__attribute__((address_space(3))) unsigned int*)l,
        16, 0, 0);
}

// ---------------- Pass 0: f32 -> bf16, pre-swizzled; preds x (10/ln2) ----------------
__global__ __launch_bounds__(256) void convert_kernel(
    const float* __restrict__ q1, const float* __restrict__ k2,
    const float* __restrict__ q2, const float* __restrict__ k1,
    const int* __restrict__ lq1, const int* __restrict__ lk2,
    const int* __restrict__ lq2, const int* __restrict__ lk1,
    ushort* __restrict__ wsbf)
{
    const int idx    = blockIdx.x * 256 + threadIdx.x;
    const int tensor = idx >> 20;
    const int rem    = idx & 1048575;
    const int t      = rem >> 9;
    const int r2     = rem & 511;
    const int b      = r2 >> 5;
    const int d8     = (r2 & 31) * 8;
    const int m = (tensor < 2) ? min(lq1[b], lk2[b]) : min(lq2[b], lk1[b]);
    if (t >= m) return;

    const float* src = (tensor == 0) ? q1 : (tensor == 1) ? k2 : (tensor == 2) ? q2 : k1;
    const float scale = (tensor == 0 || tensor == 2) ? SCALE_LOG2 : 1.0f;
    const size_t off = (size_t)t * BD + (size_t)b * D_DIM + d8;
    const float4 v0 = *reinterpret_cast<const float4*>(&src[off]);
    const float4 v1 = *reinterpret_cast<const float4*>(&src[off + 4]);
    ushort8 h;
    h[0] = f2bf(v0.x * scale); h[1] = f2bf(v0.y * scale);
    h[2] = f2bf(v0.z * scale); h[3] = f2bf(v0.w * scale);
    h[4] = f2bf(v1.x * scale); h[5] = f2bf(v1.y * scale);
    h[6] = f2bf(v1.z * scale); h[7] = f2bf(v1.w * scale);
    const size_t TBD = (size_t)T_DIM * BD;
    ushort* dst = &wsbf[(size_t)tensor * TBD + (size_t)t * BD + (size_t)b * D_DIM
                        + (d8 ^ ((t & 15) << 3))];
    *reinterpret_cast<ushort8*>(dst) = h;
}

// ---------------- Phase A: counted-vmcnt pipeline, s-split waves ----------------
// 8 waves = 4 t-groups x 2 s-halves. Wave (tg,sh) computes 32 t-rows x its own
// 32 s-cols -> halves LDS-port traffic. 3-buffer staging: prefetch st+2 while
// computing st; raw s_barrier + s_waitcnt vmcnt(4) keeps next stage's loads in
// flight across the barrier (T3/T4).
__global__ __launch_bounds__(512) void partial_lse_bf_kernel(
    const ushort* __restrict__ wsbf,
    const int* __restrict__ len_q1, const int* __restrict__ len_k2,
    const int* __restrict__ len_q2, const int* __restrict__ len_k1,
    float2* __restrict__ partial, float* __restrict__ diag)
{
    const int pair = blockIdx.z / NS;
    const int sc   = blockIdx.z % NS;
    const int b    = blockIdx.y;
    const int t0   = blockIdx.x * BMA;

    const int lp = (pair == 0) ? len_q1[b] : len_q2[b];
    const int lt = (pair == 0) ? len_k2[b] : len_k1[b];
    const int m  = min(lp, lt);
    const int s_start = sc * CHUNK;
    if (t0 >= m || s_start >= m) return;   // block-uniform early exit
    const int s_hi = min(m, s_start + CHUNK);
    const int pb = pair * B_DIM + b;

    const size_t TBD = (size_t)T_DIM * BD;
    const ushort* pred = wsbf + (size_t)(pair ? 2 : 0) * TBD;
    const ushort* targ = wsbf + (size_t)(pair ? 3 : 1) * TBD;

    __shared__ ushort tls[3 * BNA * 256];   // 3 x 32KB

    const int tid = threadIdx.x;
    const int w   = tid >> 6;     // wave 0..7
    const int l   = tid & 63;
    const int c   = l & 15;
    const int g   = l >> 4;
    const int tg  = w >> 1;       // t-group 0..3
    const int sh  = w & 1;        // s-half 0..1

    // ---- prologue 1: stage the 128-row pred tile coalesced into buffers 0,1
    #pragma unroll
    for (int h = 0; h < 2; ++h)
        #pragma unroll
        for (int q = 0; q < 4; ++q) {
            const int pr = t0 + 64 * h + 8 * w + 2 * q + (l >> 5);
            gload_lds16(&pred[(size_t)pr * BD + (size_t)b * D_DIM + (l & 31) * 8],
                        &tls[h * (BNA * 256) + (4 * w + q) * 512]);
        }
    asm volatile("s_waitcnt vmcnt(0)" ::: "memory");
    __builtin_amdgcn_s_barrier();

    // ---- extract A-fragments (pre-scaled, pre-swizzled image)
    bf16x8 afrag[2][8];
    #pragma unroll
    for (int i = 0; i < 2; ++i) {
        const int ar = 32 * tg + 16 * i + c;          // 0..127; (ar & 15) == c
        const ushort* base = &tls[(ar >> 6) * (BNA * 256) + ((ar & 63) << 8)];
        #pragma unroll
        for (int kk = 0; kk < 8; ++kk) {
            const int d = g * 8 + kk * 32;
            afrag[i][kk] = *reinterpret_cast<const bf16x8*>(&base[d ^ (c << 3)]);
        }
    }
    __syncthreads();   // all waves done reading pred; buffers reusable

    // ---- prologue 2: issue stages 0,1
    const int nstage = (s_hi - s_start + BNA - 1) / BNA;
    #pragma unroll
    for (int q = 0; q < 4; ++q) {
        const int r = 8 * w + 2 * q + (l >> 5);
        gload_lds16(&targ[(size_t)(s_start + r) * BD + (size_t)b * D_DIM + (l & 31) * 8],
                    &tls[(4 * w + q) * 512]);
    }
    if (nstage > 1) {
        #pragma unroll
        for (int q = 0; q < 4; ++q) {
            const int r = 8 * w + 2 * q + (l >> 5);
            gload_lds16(&targ[(size_t)(s_start + BNA + r) * BD + (size_t)b * D_DIM + (l & 31) * 8],
                        &tls[(BNA * 256) + (4 * w + q) * 512]);
        }
    }

    float tmax[2][4], tsum[2][4], dg[2][4];
    #pragma unroll
    for (int i = 0; i < 2; ++i)
        #pragma unroll
        for (int rr = 0; rr < 4; ++rr) {
            tmax[i][rr] = NEG_INF_F; tsum[i][rr] = 0.0f; dg[i][rr] = NEG_INF_F;
        }

    asm volatile("s_waitcnt vmcnt(0)" ::: "memory");
    __builtin_amdgcn_sched_barrier(0);
    __builtin_amdgcn_s_barrier();
    __builtin_amdgcn_sched_barrier(0);

    int cb = 0;   // buffer holding current stage
    for (int st = 0; st < nstage; ++st) {
        const int s0 = s_start + st * BNA;
        const bool pf = (st + 2 < nstage);
        if (pf) {
            int db = cb - 1; if (db < 0) db = 2;   // (cb+2)%3
            #pragma unroll
            for (int q = 0; q < 4; ++q) {
                const int r = 8 * w + 2 * q + (l >> 5);
                gload_lds16(&targ[(size_t)(s0 + 2 * BNA + r) * BD + (size_t)b * D_DIM + (l & 31) * 8],
                            &tls[db * (BNA * 256) + (4 * w + q) * 512]);
            }
        }

        const ushort* buf = &tls[cb * (BNA * 256)];
        f32x4 acc[2][2];
        #pragma unroll
        for (int i = 0; i < 2; ++i)
            #pragma unroll
            for (int j = 0; j < 2; ++j)
                acc[i][j] = (f32x4){0.f, 0.f, 0.f, 0.f};

        #pragma unroll
        for (int kk = 0; kk < 8; ++kk) {
            bf16x8 bfrag[2];
            #pragma unroll
            for (int j = 0; j < 2; ++j) {
                const int r = 32 * sh + 16 * j + c;
                const int d = g * 8 + kk * 32;
                bfrag[j] = *reinterpret_cast<const bf16x8*>(&buf[(r << 8) + (d ^ (c << 3))]);
            }
            #pragma unroll
            for (int i = 0; i < 2; ++i)
                #pragma unroll
                for (int j = 0; j < 2; ++j)
                    acc[i][j] = __builtin_amdgcn_mfma_f32_16x16x32_bf16(
                        afrag[i][kk], bfrag[j], acc[i][j], 0, 0, 0);
        }

        // ---- thread-local online LSE (log2 domain, 2 cols/row/stage)
        #pragma unroll
        for (int i = 0; i < 2; ++i) {
            #pragma unroll
            for (int rr = 0; rr < 4; ++rr) {
                const int trow = t0 + 32 * tg + 16 * i + 4 * g + rr;
                const int s0c  = s0 + 32 * sh + c;
                float v0 = (s0c      < m) ? acc[i][0][rr] : NEG_INF_F;
                float v1 = (s0c + 16 < m) ? acc[i][1][rr] : NEG_INF_F;
                if (s0c      == trow) dg[i][rr] = v0;
                if (s0c + 16 == trow) dg[i][rr] = v1;
                const float cmax = fmaxf(v0, v1);
                const float nmax = fmaxf(tmax[i][rr], cmax);
                const float add  = exp2f(v0 - nmax) + exp2f(v1 - nmax);
                tsum[i][rr] = tsum[i][rr] * exp2f(tmax[i][rr] - nmax) + add;
                tmax[i][rr] = nmax;
            }
        }

        if (pf) { asm volatile("s_waitcnt vmcnt(4)" ::: "memory"); }
        else    { asm volatile("s_waitcnt vmcnt(0)" ::: "memory"); }
        __builtin_amdgcn_sched_barrier(0);
        __builtin_amdgcn_s_barrier();
        __builtin_amdgcn_sched_barrier(0);
        ++cb; if (cb == 3) cb = 0;
    }

    // ---- 16-lane LSE merge + writes (entry index = sc*2 + sh, stride 2*NS)
    const bool own_diag = (t0 >= s_start) && (t0 + BMA <= s_start + CHUNK);
    #pragma unroll
    for (int i = 0; i < 2; ++i) {
        #pragma unroll
        for (int rr = 0; rr < 4; ++rr) {
            float M = tmax[i][rr], S = tsum[i][rr];
            #pragma unroll
            for (int msk = 1; msk < 16; msk <<= 1) {
                const float Mo = __shfl_xor(M, msk, 64);
                const float So = __shfl_xor(S, msk, 64);
                const float nM = fmaxf(M, Mo);
                S = S * exp2f(M - nM) + So * exp2f(Mo - nM);
                M = nM;
            }
            float d = dg[i][rr];
            #pragma unroll
            for (int msk = 1; msk < 16; msk <<= 1)
                d = fmaxf(d, __shfl_xor(d, msk, 64));
            if (c == 0) {
                const int trow = t0 + 32 * tg + 16 * i + 4 * g + rr;
                partial[((size_t)(pb << 11) + trow) * (2 * NS) + sc * 2 + sh] = make_float2(M, S);
                if (own_diag && d > -1.0e29f) diag[(pb << 11) + trow] = d;
            }
        }
    }
}

// ---------------- Phase A fallback (f32 inputs, log2 domain) ----------------
__global__ __launch_bounds__(256) void partial_lse_f32_kernel(
    const float* __restrict__ q1, const float* __restrict__ k2,
    const float* __restrict__ q2, const float* __restrict__ k1,
    const int* __restrict__ len_q1, const int* __restrict__ len_k2,
    const int* __restrict__ len_q2, const int* __restrict__ len_k1,
    float2* __restrict__ partial, float* __restrict__ diag,
    int chunk, int ns)
{
    const int pair = blockIdx.z / ns;
    const int sc   = blockIdx.z % ns;
    const int b    = blockIdx.y;
    const int t0   = blockIdx.x * 128;

    const float* pred = (pair == 0) ? q1 : q2;
    const float* targ = (pair == 0) ? k2 : k1;
    const int lp = (pair == 0) ? len_q1[b] : len_q2[b];
    const int lt = (pair == 0) ? len_k2[b] : len_k1[b];
    const int m  = min(lp, lt);
    const int s_start = sc * chunk;
    if (t0 >= m || s_start >= m) return;
    const int s_hi = min(m, s_start + chunk);
    const int pb = pair * B_DIM + b;

    __shared__ ushort tlf[BNA * 256];

    const int tid = threadIdx.x;
    const int w   = tid >> 6;
    const int l   = tid & 63;
    const int c   = l & 15;
    const int g   = l >> 4;

    bf16x8 afrag[2][8];
    #pragma unroll
    for (int i = 0; i < 2; ++i) {
        const float* base = &pred[(size_t)(t0 + 32 * w + 16 * i + c) * BD + (size_t)b * D_DIM];
        #pragma unroll
        for (int kk = 0; kk < 8; ++kk) {
            const int d = g * 8 + kk * 32;
            const float4 v0 = *reinterpret_cast<const float4*>(base + d);
            const float4 v1 = *reinterpret_cast<const float4*>(base + d + 4);
            bf16x8 av;
            av[0] = (short)f2bf(v0.x * SCALE_LOG2); av[1] = (short)f2bf(v0.y * SCALE_LOG2);
            av[2] = (short)f2bf(v0.z * SCALE_LOG2); av[3] = (short)f2bf(v0.w * SCALE_LOG2);
            av[4] = (short)f2bf(v1.x * SCALE_LOG2); av[5] = (short)f2bf(v1.y * SCALE_LOG2);
            av[6] = (short)f2bf(v1.z * SCALE_LOG2); av[7] = (short)f2bf(v1.w * SCALE_LOG2);
            afrag[i][kk] = av;
        }
    }

    float tmax[2][4], tsum[2][4], dg[2][4];
    #pragma unroll
    for (int i = 0; i < 2; ++i)
        #pragma unroll
        for (int rr = 0; rr < 4; ++rr) {
            tmax[i][rr] = NEG_INF_F; tsum[i][rr] = 0.0f; dg[i][rr] = NEG_INF_F;
        }

    for (int s0 = s_start; s0 < s_hi; s0 += BNA) {
        __syncthreads();
        #pragma unroll
        for (int v = 0; v < 16; ++v) {
            const int f  = v * 256 + tid;
            const int r  = f >> 6;
            const int d0 = (f & 63) * 4;
            const float4 vv = *reinterpret_cast<const float4*>(
                &targ[(size_t)(s0 + r) * BD + (size_t)b * D_DIM + d0]);
            ushort4 h;
            h.x = f2bf(vv.x); h.y = f2bf(vv.y); h.z = f2bf(vv.z); h.w = f2bf(vv.w);
            *reinterpret_cast<ushort4*>(&tlf[(r << 8) + (d0 ^ ((r & 15) << 3))]) = h;
        }
        __syncthreads();

        f32x4 acc[2][4];
        #pragma unroll
        for (int i = 0; i < 2; ++i)
            #pragma unroll
            for (int j = 0; j < 4; ++j)
                acc[i][j] = (f32x4){0.f, 0.f, 0.f, 0.f};

        #pragma unroll
        for (int kk = 0; kk < 8; ++kk) {
            bf16x8 bfrag[4];
            #pragma unroll
            for (int j = 0; j < 4; ++j) {
                const int r = 16 * j + c;
                const int d = g * 8 + kk * 32;
                bfrag[j] = *reinterpret_cast<const bf16x8*>(&tlf[(r << 8) + (d ^ (c << 3))]);
            }
            #pragma unroll
            for (int i = 0; i < 2; ++i)
                #pragma unroll
                for (int j = 0; j < 4; ++j)
                    acc[i][j] = __builtin_amdgcn_mfma_f32_16x16x32_bf16(
                        afrag[i][kk], bfrag[j], acc[i][j], 0, 0, 0);
        }

        #pragma unroll
        for (int i = 0; i < 2; ++i) {
            #pragma unroll
            for (int rr = 0; rr < 4; ++rr) {
                const int trow = t0 + 32 * w + 16 * i + 4 * g + rr;
                float lg[4];
                float cmax = NEG_INF_F;
                #pragma unroll
                for (int j = 0; j < 4; ++j) {
                    const int s = s0 + 16 * j + c;
                    float v = acc[i][j][rr];
                    v = (s < m) ? v : NEG_INF_F;
                    if (s == trow) dg[i][rr] = v;
                    lg[j] = v;
                    cmax = fmaxf(cmax, v);
                }
                const float nmax = fmaxf(tmax[i][rr], cmax);
                const float add = exp2f(lg[0] - nmax) + exp2f(lg[1] - nmax)
                                + exp2f(lg[2] - nmax) + exp2f(lg[3] - nmax);
                tsum[i][rr] = tsum[i][rr] * exp2f(tmax[i][rr] - nmax) + add;
                tmax[i][rr] = nmax;
            }
        }
    }

    const bool own_diag = (t0 >= s_start) && (t0 + 128 <= s_start + chunk);
    #pragma unroll
    for (int i = 0; i < 2; ++i) {
        #pragma unroll
        for (int rr = 0; rr < 4; ++rr) {
            float M = tmax[i][rr], S = tsum[i][rr];
            #pragma unroll
            for (int msk = 1; msk < 16; msk <<= 1) {
                const float Mo = __shfl_xor(M, msk, 64);
                const float So = __shfl_xor(S, msk, 64);
                const float nM = fmaxf(M, Mo);
                S = S * exp2f(M - nM) + So * exp2f(Mo - nM);
                M = nM;
            }
            float d = dg[i][rr];
            #pragma unroll
            for (int msk = 1; msk < 16; msk <<= 1)
                d = fmaxf(d, __shfl_xor(d, msk, 64));
            if (c == 0) {
                const int trow = t0 + 32 * w + 16 * i + 4 * g + rr;
                partial[((size_t)(pb << 11) + trow) * ns + sc] = make_float2(M, S);
                if (own_diag) diag[(pb << 11) + trow] = d;
            }
        }
    }
}

// ---------------- Phase B: merge partial LSEs (log2 domain) ----------------
__global__ __launch_bounds__(256) void combine_kernel(
    const int* __restrict__ len_q1, const int* __restrict__ len_k2,
    const int* __restrict__ len_q2, const int* __restrict__ len_k1,
    const float2* __restrict__ partial, const float* __restrict__ diag,
    float* __restrict__ per_sample, int chunk, int stride, int mult)
{
    const int pb   = blockIdx.x;
    const int pair = pb >> 4;
    const int b    = pb & 15;
    const int lp = (pair == 0) ? len_q1[b] : len_q2[b];
    const int lt = (pair == 0) ? len_k2[b] : len_k1[b];
    const int m  = min(lp, lt);

    float local = 0.0f;
    if (m > 0) {
        const int nch = mult * ((m + chunk - 1) / chunk);
        for (int t = threadIdx.x; t < m; t += 256) {
            float M = NEG_INF_F, S = 0.0f;
            for (int e = 0; e < nch; ++e) {
                const float2 p = partial[((size_t)(pb << 11) + t) * stride + e];
                const float nM = fmaxf(M, p.x);
                S = S * exp2f(M - nM) + p.y * exp2f(p.x - nM);
                M = nM;
            }
            local += LN2F * ((__log2f(S) + M) - diag[(pb << 11) + t]);
        }
    }

    __shared__ float ws4[4];
    #pragma unroll
    for (int msk = 1; msk < 64; msk <<= 1)
        local += __shfl_xor(local, msk, 64);
    if ((threadIdx.x & 63) == 0) ws4[threadIdx.x >> 6] = local;
    __syncthreads();
    if (threadIdx.x == 0) {
        const float tot = ws4[0] + ws4[1] + ws4[2] + ws4[3];
        per_sample[pb] = (m > 0) ? (tot / (float)m) : 0.0f;
    }
}

__global__ void finalize_kernel(
    const int* __restrict__ len_q1, const int* __restrict__ len_k2,
    const int* __restrict__ len_q2, const int* __restrict__ len_k1,
    const float* __restrict__ per_sample, float* __restrict__ out)
{
    if (threadIdx.x != 0 || blockIdx.x != 0) return;
    float losses[2];
    #pragma unroll
    for (int p = 0; p < 2; ++p) {
        float tot = 0.0f, nv = 0.0f;
        for (int b = 0; b < B_DIM; ++b) {
            const int lp = (p == 0) ? len_q1[b] : len_q2[b];
            const int lt = (p == 0) ? len_k2[b] : len_k1[b];
            const int mm = min(lp, lt);
            if (mm > 0) { tot += per_sample[p * B_DIM + b]; nv += 1.0f; }
        }
        losses[p] = (nv > 0.0f) ? (tot / nv) : 0.0f;
    }
    out[0] = 0.5f * (losses[0] + losses[1]);
}

extern "C" void kernel_launch(void* const* d_in, const int* in_sizes, int n_in,
                              void* d_out, int out_size, void* d_ws, size_t ws_size,
                              hipStream_t stream) {
    const float* q1 = (const float*)d_in[0];
    const float* k2 = (const float*)d_in[1];
    const float* q2 = (const float*)d_in[2];
    const float* k1 = (const float*)d_in[3];
    const int* lq1 = (const int*)d_in[6];
    const int* lk2 = (const int*)d_in[7];
    const int* lq2 = (const int*)d_in[8];
    const int* lk1 = (const int*)d_in[9];
    float* out = (float*)d_out;

    const size_t TBD  = (size_t)T_DIM * BD;
    const size_t rows = (size_t)2 * B_DIM * T_DIM;      // 65536
    const size_t bfbytes = 4 * TBD * sizeof(ushort);    // 67.1 MB
    const size_t pbytes  = rows * (2 * NS) * sizeof(float2);
    const size_t need_pre = bfbytes + pbytes + rows * sizeof(float) + 256;

    if (ws_size >= need_pre) {
        ushort* wsbf       = (ushort*)d_ws;
        float2* partial    = (float2*)((char*)d_ws + bfbytes);
        float*  diag       = (float*)((char*)partial + pbytes);
        float*  per_sample = diag + rows;

        convert_kernel<<<16384, 256, 0, stream>>>(q1, k2, q2, k1, lq1, lk2, lq2, lk1, wsbf);

        dim3 gridA(T_DIM / BMA, B_DIM, 2 * NS);   // 16 x 16 x 8
        partial_lse_bf_kernel<<<gridA, 512, 0, stream>>>(
            wsbf, lq1, lk2, lq2, lk1, partial, diag);

        combine_kernel<<<32, 256, 0, stream>>>(
            lq1, lk2, lq2, lk1, partial, diag, per_sample, CHUNK, 2 * NS, 2);
        finalize_kernel<<<1, 64, 0, stream>>>(lq1, lk2, lq2, lk1, per_sample, out);
    } else {
        int ns = 8;
        while (ns > 1) {
            const size_t need = rows * ns * sizeof(float2) + rows * sizeof(float) + 256;
            if (need <= ws_size) break;
            ns >>= 1;
        }
        const int chunk = T_DIM / ns;
        float2* partial    = (float2*)d_ws;
        float*  diag       = (float*)((char*)d_ws + rows * ns * sizeof(float2));
        float*  per_sample = diag + rows;

        dim3 gridA(T_DIM / 128, B_DIM, 2 * ns);
        partial_lse_f32_kernel<<<gridA, 256, 0, stream>>>(
            q1, k2, q2, k1, lq1, lk2, lq2, lk1, partial, diag, chunk, ns);

        combine_kernel<<<32, 256, 0, stream>>>(
            lq1, lk2, lq2, lk1, partial, diag, per_sample, chunk, ns, 1);
        finalize_kernel<<<1, 64, 0, stream>>>(lq1, lk2, lq2, lk1, per_sample, out);
    }
}

// Round 9
// 90.118 us; speedup vs baseline: 1.1735x; 1.1735x over previous
//
#include <hip/hip_runtime.h>
#include <hip/hip_bf16.h>
#include <cmath>

#define T_DIM 2048
#define B_DIM 16
#define D_DIM 256
#define BD (B_DIM * D_DIM)      // f32 input row stride (t-major (T,B,D))
#define ROWU 256                // image row length in ushorts
#define SLAB (T_DIM * ROWU)     // per-(tensor,b) slab in ushorts
#define BM 128                  // t-rows per block
#define BN 64                   // s-rows per stage
#define NS 8                    // s-chunks (chunk = 256)
#define CHUNK (T_DIM / NS)
#define NEG_INF_F (-1e30f)
#define SCALE_LOG2 14.4269504088896f  // 10 / ln(2)
#define LN2F 0.6931471805599453f

typedef __attribute__((ext_vector_type(8))) short bf16x8;
typedef __attribute__((ext_vector_type(8))) unsigned short ushort8;
typedef __attribute__((ext_vector_type(4))) float f32x4;

static __device__ __forceinline__ ushort f2bf(float f) {
    union { float f; unsigned int u; } x; x.f = f;
    unsigned int r = (x.u + 0x7FFFu + ((x.u >> 16) & 1u)) >> 16;  // RNE
    return (ushort)r;
}

static __device__ __forceinline__ void gload_lds16(const ushort* g, ushort* l) {
    __builtin_amdgcn_global_load_lds(
        (const __attribute__((address_space(1))) unsigned int*)g,
        (__attribute__((address_space(3))) unsigned int*)l,
        16, 0, 0);
}

// ---- Pass 0: f32 (T,B,D) -> bf16 batch-major image [(tensor,b)][t][D],
// in-row XOR-swizzled (d ^ ((t&15)<<3)); preds scaled by 10/ln2.
__global__ __launch_bounds__(256) void convert_kernel(
    const float* __restrict__ q1, const float* __restrict__ k2,
    const float* __restrict__ q2, const float* __restrict__ k1,
    const int* __restrict__ lq1, const int* __restrict__ lk2,
    const int* __restrict__ lq2, const int* __restrict__ lk1,
    ushort* __restrict__ wsbf)
{
    const int idx    = blockIdx.x * 256 + threadIdx.x;
    const int tensor = idx >> 20;
    const int rem    = idx & 1048575;
    const int t      = rem >> 9;
    const int r2     = rem & 511;
    const int b      = r2 >> 5;
    const int d8     = (r2 & 31) * 8;
    const int m = (tensor < 2) ? min(lq1[b], lk2[b]) : min(lq2[b], lk1[b]);
    if (t >= m) return;

    const float* src = (tensor == 0) ? q1 : (tensor == 1) ? k2 : (tensor == 2) ? q2 : k1;
    const float scale = (tensor == 0 || tensor == 2) ? SCALE_LOG2 : 1.0f;
    const size_t off = (size_t)t * BD + (size_t)b * D_DIM + d8;
    const float4 v0 = *reinterpret_cast<const float4*>(&src[off]);
    const float4 v1 = *reinterpret_cast<const float4*>(&src[off + 4]);
    ushort8 h;
    h[0] = f2bf(v0.x * scale); h[1] = f2bf(v0.y * scale);
    h[2] = f2bf(v0.z * scale); h[3] = f2bf(v0.w * scale);
    h[4] = f2bf(v1.x * scale); h[5] = f2bf(v1.y * scale);
    h[6] = f2bf(v1.z * scale); h[7] = f2bf(v1.w * scale);
    ushort* dst = &wsbf[(size_t)(tensor * B_DIM + b) * SLAB + (size_t)t * ROWU
                        + (d8 ^ ((t & 15) << 3))];
    *reinterpret_cast<ushort8*>(dst) = h;
}

// ---- Phase A: R5 shape + batch-major image + afrag-via-LDS (no strided gathers)
__global__ __launch_bounds__(256) void partial_lse_bf_kernel(
    const ushort* __restrict__ wsbf,
    const int* __restrict__ len_q1, const int* __restrict__ len_k2,
    const int* __restrict__ len_q2, const int* __restrict__ len_k1,
    float2* __restrict__ partial, float* __restrict__ diag)
{
    const int pair = blockIdx.z / NS;
    const int sc   = blockIdx.z % NS;
    const int b    = blockIdx.y;
    const int t0   = blockIdx.x * BM;

    const int lp = (pair == 0) ? len_q1[b] : len_q2[b];
    const int lt = (pair == 0) ? len_k2[b] : len_k1[b];
    const int m  = min(lp, lt);
    const int s_start = sc * CHUNK;
    if (t0 >= m || s_start >= m) return;   // block-uniform early exit
    const int s_hi = min(m, s_start + CHUNK);
    const int pb = pair * B_DIM + b;

    const ushort* pred = wsbf + (size_t)((pair ? 2 : 0) * B_DIM + b) * SLAB;
    const ushort* targ = wsbf + (size_t)((pair ? 3 : 1) * B_DIM + b) * SLAB;

    __shared__ ushort tls[2 * BN * ROWU];   // 2 x 32KB

    const int tid = threadIdx.x;
    const int w   = tid >> 6;
    const int l   = tid & 63;
    const int c   = l & 15;
    const int g   = l >> 4;

    // ---- prologue 1: stage 128-row pred tile (64KB CONTIGUOUS) into both buffers
    #pragma unroll
    for (int q = 0; q < 16; ++q) {
        const int chunk16 = q * 4 + w;               // 64 x 1KB chunks
        gload_lds16(&pred[(size_t)t0 * ROWU + chunk16 * 512 + l * 8],
                    &tls[chunk16 * 512]);
    }
    __syncthreads();   // drains vmcnt(0)

    // ---- extract A-fragments from LDS (swizzled rows; ar&15 == c)
    bf16x8 afrag[2][8];
    #pragma unroll
    for (int i = 0; i < 2; ++i) {
        const int ar = 32 * w + 16 * i + c;          // 0..127
        #pragma unroll
        for (int kk = 0; kk < 8; ++kk) {
            const int d = g * 8 + kk * 32;
            afrag[i][kk] = *reinterpret_cast<const bf16x8*>(&tls[(ar << 8) + (d ^ (c << 3))]);
        }
    }
    __syncthreads();   // all waves done reading pred; buffers reusable

    // ---- prologue 2: issue targ stages 0 (buf0) and 1 (buf1); rows contiguous
    const int nstage = (s_hi - s_start + BN - 1) / BN;
    #pragma unroll
    for (int q = 0; q < 8; ++q) {
        const int chunk16 = q * 4 + w;               // 32 x 1KB chunks
        gload_lds16(&targ[(size_t)s_start * ROWU + chunk16 * 512 + l * 8],
                    &tls[chunk16 * 512]);
    }
    if (nstage > 1) {
        #pragma unroll
        for (int q = 0; q < 8; ++q) {
            const int chunk16 = q * 4 + w;
            gload_lds16(&targ[(size_t)(s_start + BN) * ROWU + chunk16 * 512 + l * 8],
                        &tls[BN * ROWU + chunk16 * 512]);
        }
    }

    float tmax[2][4], tsum[2][4], dg[2][4];
    #pragma unroll
    for (int i = 0; i < 2; ++i)
        #pragma unroll
        for (int rr = 0; rr < 4; ++rr) {
            tmax[i][rr] = NEG_INF_F; tsum[i][rr] = 0.0f; dg[i][rr] = NEG_INF_F;
        }

    __syncthreads();   // stage 0 (and 1) issued; drain ensures stage 0 landed
    int cur = 0;

    for (int st = 0; st < nstage; ++st) {
        const int s0 = s_start + st * BN;
        // prefetch stage st+1 already in flight; issue st+1 replacement (st+2's
        // slot) pattern: R5 style — issue NEXT stage into other buffer now
        if (st + 2 < nstage + 1 && st + 1 < nstage && st >= 1) { /* handled below */ }

        // (R5 flow: at each iteration, prefetch s0+BN into the other buffer
        //  BEFORE compute — stage 0/1 pre-issued above, so from st>=1 we issue st+1)
        if (st >= 1 && st + 1 < nstage) {
            const int nxt = cur ^ 1;   // buffer of st-1, now free
            #pragma unroll
            for (int q = 0; q < 8; ++q) {
                const int chunk16 = q * 4 + w;
                gload_lds16(&targ[(size_t)(s0 + BN) * ROWU + chunk16 * 512 + l * 8],
                            &tls[nxt * (BN * ROWU) + chunk16 * 512]);
            }
        }

        const ushort* buf = &tls[cur * (BN * ROWU)];
        f32x4 acc[2][4];
        #pragma unroll
        for (int i = 0; i < 2; ++i)
            #pragma unroll
            for (int j = 0; j < 4; ++j)
                acc[i][j] = (f32x4){0.f, 0.f, 0.f, 0.f};

        #pragma unroll
        for (int kk = 0; kk < 8; ++kk) {
            bf16x8 bfrag[4];
            #pragma unroll
            for (int j = 0; j < 4; ++j) {
                const int r = 16 * j + c;
                const int d = g * 8 + kk * 32;
                bfrag[j] = *reinterpret_cast<const bf16x8*>(&buf[(r << 8) + (d ^ (c << 3))]);
            }
            #pragma unroll
            for (int i = 0; i < 2; ++i)
                #pragma unroll
                for (int j = 0; j < 4; ++j)
                    acc[i][j] = __builtin_amdgcn_mfma_f32_16x16x32_bf16(
                        afrag[i][kk], bfrag[j], acc[i][j], 0, 0, 0);
        }

        // ---- thread-local online LSE (log2 domain)
        #pragma unroll
        for (int i = 0; i < 2; ++i) {
            #pragma unroll
            for (int rr = 0; rr < 4; ++rr) {
                const int trow = t0 + 32 * w + 16 * i + 4 * g + rr;
                float lg[4];
                float cmax = NEG_INF_F;
                #pragma unroll
                for (int j = 0; j < 4; ++j) {
                    const int s = s0 + 16 * j + c;
                    float v = acc[i][j][rr];
                    v = (s < m) ? v : NEG_INF_F;
                    if (s == trow) dg[i][rr] = v;
                    lg[j] = v;
                    cmax = fmaxf(cmax, v);
                }
                const float nmax = fmaxf(tmax[i][rr], cmax);
                const float add = exp2f(lg[0] - nmax) + exp2f(lg[1] - nmax)
                                + exp2f(lg[2] - nmax) + exp2f(lg[3] - nmax);
                tsum[i][rr] = tsum[i][rr] * exp2f(tmax[i][rr] - nmax) + add;
                tmax[i][rr] = nmax;
            }
        }

        __syncthreads();   // cur reads done + in-flight prefetch landed
        cur ^= 1;
    }

    // ---- 16-lane LSE merge + writes
    const bool own_diag = (t0 >= s_start) && (t0 + BM <= s_start + CHUNK);
    #pragma unroll
    for (int i = 0; i < 2; ++i) {
        #pragma unroll
        for (int rr = 0; rr < 4; ++rr) {
            float M = tmax[i][rr], S = tsum[i][rr];
            #pragma unroll
            for (int msk = 1; msk < 16; msk <<= 1) {
                const float Mo = __shfl_xor(M, msk, 64);
                const float So = __shfl_xor(S, msk, 64);
                const float nM = fmaxf(M, Mo);
                S = S * exp2f(M - nM) + So * exp2f(Mo - nM);
                M = nM;
            }
            float d = dg[i][rr];
            #pragma unroll
            for (int msk = 1; msk < 16; msk <<= 1)
                d = fmaxf(d, __shfl_xor(d, msk, 64));
            if (c == 0) {
                const int trow = t0 + 32 * w + 16 * i + 4 * g + rr;
                partial[((size_t)(pb << 11) + trow) * NS + sc] = make_float2(M, S);
                if (own_diag) diag[(pb << 11) + trow] = d;
            }
        }
    }
}

// ---- Phase A fallback (f32 inputs direct, log2 domain) ----
__global__ __launch_bounds__(256) void partial_lse_f32_kernel(
    const float* __restrict__ q1, const float* __restrict__ k2,
    const float* __restrict__ q2, const float* __restrict__ k1,
    const int* __restrict__ len_q1, const int* __restrict__ len_k2,
    const int* __restrict__ len_q2, const int* __restrict__ len_k1,
    float2* __restrict__ partial, float* __restrict__ diag,
    int chunk, int ns)
{
    const int pair = blockIdx.z / ns;
    const int sc   = blockIdx.z % ns;
    const int b    = blockIdx.y;
    const int t0   = blockIdx.x * 128;

    const float* pred = (pair == 0) ? q1 : q2;
    const float* targ = (pair == 0) ? k2 : k1;
    const int lp = (pair == 0) ? len_q1[b] : len_q2[b];
    const int lt = (pair == 0) ? len_k2[b] : len_k1[b];
    const int m  = min(lp, lt);
    const int s_start = sc * chunk;
    if (t0 >= m || s_start >= m) return;
    const int s_hi = min(m, s_start + chunk);
    const int pb = pair * B_DIM + b;

    __shared__ ushort tlf[BN * 256];

    const int tid = threadIdx.x;
    const int w   = tid >> 6;
    const int l   = tid & 63;
    const int c   = l & 15;
    const int g   = l >> 4;

    bf16x8 afrag[2][8];
    #pragma unroll
    for (int i = 0; i < 2; ++i) {
        const float* base = &pred[(size_t)(t0 + 32 * w + 16 * i + c) * BD + (size_t)b * D_DIM];
        #pragma unroll
        for (int kk = 0; kk < 8; ++kk) {
            const int d = g * 8 + kk * 32;
            const float4 v0 = *reinterpret_cast<const float4*>(base + d);
            const float4 v1 = *reinterpret_cast<const float4*>(base + d + 4);
            bf16x8 av;
            av[0] = (short)f2bf(v0.x * SCALE_LOG2); av[1] = (short)f2bf(v0.y * SCALE_LOG2);
            av[2] = (short)f2bf(v0.z * SCALE_LOG2); av[3] = (short)f2bf(v0.w * SCALE_LOG2);
            av[4] = (short)f2bf(v1.x * SCALE_LOG2); av[5] = (short)f2bf(v1.y * SCALE_LOG2);
            av[6] = (short)f2bf(v1.z * SCALE_LOG2); av[7] = (short)f2bf(v1.w * SCALE_LOG2);
            afrag[i][kk] = av;
        }
    }

    float tmax[2][4], tsum[2][4], dg[2][4];
    #pragma unroll
    for (int i = 0; i < 2; ++i)
        #pragma unroll
        for (int rr = 0; rr < 4; ++rr) {
            tmax[i][rr] = NEG_INF_F; tsum[i][rr] = 0.0f; dg[i][rr] = NEG_INF_F;
        }

    for (int s0 = s_start; s0 < s_hi; s0 += BN) {
        __syncthreads();
        #pragma unroll
        for (int v = 0; v < 16; ++v) {
            const int f  = v * 256 + tid;
            const int r  = f >> 6;
            const int d0 = (f & 63) * 4;
            const float4 vv = *reinterpret_cast<const float4*>(
                &targ[(size_t)(s0 + r) * BD + (size_t)b * D_DIM + d0]);
            ushort4 h;
            h.x = f2bf(vv.x); h.y = f2bf(vv.y); h.z = f2bf(vv.z); h.w = f2bf(vv.w);
            *reinterpret_cast<ushort4*>(&tlf[(r << 8) + (d0 ^ ((r & 15) << 3))]) = h;
        }
        __syncthreads();

        f32x4 acc[2][4];
        #pragma unroll
        for (int i = 0; i < 2; ++i)
            #pragma unroll
            for (int j = 0; j < 4; ++j)
                acc[i][j] = (f32x4){0.f, 0.f, 0.f, 0.f};

        #pragma unroll
        for (int kk = 0; kk < 8; ++kk) {
            bf16x8 bfrag[4];
            #pragma unroll
            for (int j = 0; j < 4; ++j) {
                const int r = 16 * j + c;
                const int d = g * 8 + kk * 32;
                bfrag[j] = *reinterpret_cast<const bf16x8*>(&tlf[(r << 8) + (d ^ (c << 3))]);
            }
            #pragma unroll
            for (int i = 0; i < 2; ++i)
                #pragma unroll
                for (int j = 0; j < 4; ++j)
                    acc[i][j] = __builtin_amdgcn_mfma_f32_16x16x32_bf16(
                        afrag[i][kk], bfrag[j], acc[i][j], 0, 0, 0);
        }

        #pragma unroll
        for (int i = 0; i < 2; ++i) {
            #pragma unroll
            for (int rr = 0; rr < 4; ++rr) {
                const int trow = t0 + 32 * w + 16 * i + 4 * g + rr;
                float lg[4];
                float cmax = NEG_INF_F;
                #pragma unroll
                for (int j = 0; j < 4; ++j) {
                    const int s = s0 + 16 * j + c;
                    float v = acc[i][j][rr];
                    v = (s < m) ? v : NEG_INF_F;
                    if (s == trow) dg[i][rr] = v;
                    lg[j] = v;
                    cmax = fmaxf(cmax, v);
                }
                const float nmax = fmaxf(tmax[i][rr], cmax);
                const float add = exp2f(lg[0] - nmax) + exp2f(lg[1] - nmax)
                                + exp2f(lg[2] - nmax) + exp2f(lg[3] - nmax);
                tsum[i][rr] = tsum[i][rr] * exp2f(tmax[i][rr] - nmax) + add;
                tmax[i][rr] = nmax;
            }
        }
    }

    const bool own_diag = (t0 >= s_start) && (t0 + 128 <= s_start + chunk);
    #pragma unroll
    for (int i = 0; i < 2; ++i) {
        #pragma unroll
        for (int rr = 0; rr < 4; ++rr) {
            float M = tmax[i][rr], S = tsum[i][rr];
            #pragma unroll
            for (int msk = 1; msk < 16; msk <<= 1) {
                const float Mo = __shfl_xor(M, msk, 64);
                const float So = __shfl_xor(S, msk, 64);
                const float nM = fmaxf(M, Mo);
                S = S * exp2f(M - nM) + So * exp2f(Mo - nM);
                M = nM;
            }
            float d = dg[i][rr];
            #pragma unroll
            for (int msk = 1; msk < 16; msk <<= 1)
                d = fmaxf(d, __shfl_xor(d, msk, 64));
            if (c == 0) {
                const int trow = t0 + 32 * w + 16 * i + 4 * g + rr;
                partial[((size_t)(pb << 11) + trow) * ns + sc] = make_float2(M, S);
                if (own_diag) diag[(pb << 11) + trow] = d;
            }
        }
    }
}

// ---- Phase B: merge partial LSEs (log2 domain) ----
__global__ __launch_bounds__(256) void combine_kernel(
    const int* __restrict__ len_q1, const int* __restrict__ len_k2,
    const int* __restrict__ len_q2, const int* __restrict__ len_k1,
    const float2* __restrict__ partial, const float* __restrict__ diag,
    float* __restrict__ per_sample, int chunk, int stride)
{
    const int pb   = blockIdx.x;
    const int pair = pb >> 4;
    const int b    = pb & 15;
    const int lp = (pair == 0) ? len_q1[b] : len_q2[b];
    const int lt = (pair == 0) ? len_k2[b] : len_k1[b];
    const int m  = min(lp, lt);

    float local = 0.0f;
    if (m > 0) {
        const int nch = (m + chunk - 1) / chunk;
        for (int t = threadIdx.x; t < m; t += 256) {
            float M = NEG_INF_F, S = 0.0f;
            for (int e = 0; e < nch; ++e) {
                const float2 p = partial[((size_t)(pb << 11) + t) * stride + e];
                const float nM = fmaxf(M, p.x);
                S = S * exp2f(M - nM) + p.y * exp2f(p.x - nM);
                M = nM;
            }
            local += LN2F * ((__log2f(S) + M) - diag[(pb << 11) + t]);
        }
    }

    __shared__ float ws4[4];
    #pragma unroll
    for (int msk = 1; msk < 64; msk <<= 1)
        local += __shfl_xor(local, msk, 64);
    if ((threadIdx.x & 63) == 0) ws4[threadIdx.x >> 6] = local;
    __syncthreads();
    if (threadIdx.x == 0) {
        const float tot = ws4[0] + ws4[1] + ws4[2] + ws4[3];
        per_sample[pb] = (m > 0) ? (tot / (float)m) : 0.0f;
    }
}

__global__ void finalize_kernel(
    const int* __restrict__ len_q1, const int* __restrict__ len_k2,
    const int* __restrict__ len_q2, const int* __restrict__ len_k1,
    const float* __restrict__ per_sample, float* __restrict__ out)
{
    if (threadIdx.x != 0 || blockIdx.x != 0) return;
    float losses[2];
    #pragma unroll
    for (int p = 0; p < 2; ++p) {
        float tot = 0.0f, nv = 0.0f;
        for (int b = 0; b < B_DIM; ++b) {
            const int lp = (p == 0) ? len_q1[b] : len_q2[b];
            const int lt = (p == 0) ? len_k2[b] : len_k1[b];
            const int mm = min(lp, lt);
            if (mm > 0) { tot += per_sample[p * B_DIM + b]; nv += 1.0f; }
        }
        losses[p] = (nv > 0.0f) ? (tot / nv) : 0.0f;
    }
    out[0] = 0.5f * (losses[0] + losses[1]);
}

extern "C" void kernel_launch(void* const* d_in, const int* in_sizes, int n_in,
                              void* d_out, int out_size, void* d_ws, size_t ws_size,
                              hipStream_t stream) {
    const float* q1 = (const float*)d_in[0];
    const float* k2 = (const float*)d_in[1];
    const float* q2 = (const float*)d_in[2];
    const float* k1 = (const float*)d_in[3];
    const int* lq1 = (const int*)d_in[6];
    const int* lk2 = (const int*)d_in[7];
    const int* lq2 = (const int*)d_in[8];
    const int* lk1 = (const int*)d_in[9];
    float* out = (float*)d_out;

    const size_t rows = (size_t)2 * B_DIM * T_DIM;              // 65536
    const size_t bfbytes = (size_t)4 * B_DIM * SLAB * sizeof(ushort); // 67.1 MB
    const size_t pbytes  = rows * NS * sizeof(float2);          // 4.2 MB
    const size_t need_pre = bfbytes + pbytes + rows * sizeof(float) + 256;

    if (ws_size >= need_pre) {
        ushort* wsbf       = (ushort*)d_ws;
        float2* partial    = (float2*)((char*)d_ws + bfbytes);
        float*  diag       = (float*)((char*)partial + pbytes);
        float*  per_sample = diag + rows;

        convert_kernel<<<16384, 256, 0, stream>>>(q1, k2, q2, k1, lq1, lk2, lq2, lk1, wsbf);

        dim3 gridA(T_DIM / BM, B_DIM, 2 * NS);   // 16 x 16 x 16
        partial_lse_bf_kernel<<<gridA, 256, 0, stream>>>(
            wsbf, lq1, lk2, lq2, lk1, partial, diag);

        combine_kernel<<<32, 256, 0, stream>>>(
            lq1, lk2, lq2, lk1, partial, diag, per_sample, CHUNK, NS);
        finalize_kernel<<<1, 64, 0, stream>>>(lq1, lk2, lq2, lk1, per_sample, out);
    } else {
        int ns = 8;
        while (ns > 1) {
            const size_t need = rows * ns * sizeof(float2) + rows * sizeof(float) + 256;
            if (need <= ws_size) break;
            ns >>= 1;
        }
        const int chunk = T_DIM / ns;
        float2* partial    = (float2*)d_ws;
        float*  diag       = (float*)((char*)d_ws + rows * ns * sizeof(float2));
        float*  per_sample = diag + rows;

        dim3 gridA(T_DIM / 128, B_DIM, 2 * ns);
        partial_lse_f32_kernel<<<gridA, 256, 0, stream>>>(
            q1, k2, q2, k1, lq1, lk2, lq2, lk1, partial, diag, chunk, ns);

        combine_kernel<<<32, 256, 0, stream>>>(
            lq1, lk2, lq2, lk1, partial, diag, per_sample, chunk, ns);
        finalize_kernel<<<1, 64, 0, stream>>>(lq1, lk2, lq2, lk1, per_sample, out);
    }
}